// Round 3
// baseline (2960.559 us; speedup 1.0000x reference)
//
#include <hip/hip_runtime.h>
#include <hip/hip_bf16.h>
#include <math.h>

#define LNUM  6
#define HDIM  768
#define NHEAD 12
#define DHEAD 64
#define IDIM  3072
#define NB    16
#define SEQ   512
#define MTOK  (NB*SEQ)   // 8192

typedef __bf16 bf16;
typedef __bf16 bf16x4 __attribute__((ext_vector_type(4)));
typedef __bf16 bf16x8 __attribute__((ext_vector_type(8)));
typedef float  f32x4  __attribute__((ext_vector_type(4)));

// ---- async global->LDS, 16B per lane (dest = wave-uniform base + lane*16) ----
__device__ __forceinline__ void async_copy16(const bf16* g, bf16* l) {
  __builtin_amdgcn_global_load_lds((__attribute__((address_space(1))) void*)g,
                                   (__attribute__((address_space(3))) void*)l,
                                   16, 0, 0);
}

// =====================  dtype detector  =====================
// Probes first 4096 u16 words of Wq. bf16 data: ~100% of words have exponent
// field in [90,130]. f32 data read as u16: even halves are mantissa bits
// (uniform exponent field, ~16% hit) -> ~58% total. Threshold 85%.
// flag = 1 -> inputs are float32 ; flag = 0 -> inputs are bf16.
__global__ void detect_k(const unsigned short* __restrict__ probe, int* __restrict__ flag)
{
  __shared__ int sc[4];
  const int tid = threadIdx.x;
  int cnt = 0;
#pragma unroll
  for (int j = 0; j < 16; j++) {
    const unsigned short w = probe[tid * 16 + j];
    const int e = (w >> 7) & 0xFF;
    cnt += (e >= 90 && e <= 130) ? 1 : 0;
  }
#pragma unroll
  for (int o = 32; o; o >>= 1) cnt += __shfl_xor(cnt, o);
  if ((tid & 63) == 0) sc[tid >> 6] = cnt;
  __syncthreads();
  if (tid == 0) flag[0] = ((sc[0] + sc[1] + sc[2] + sc[3]) < 3482) ? 1 : 0;
}

// =====================  1-D normalize (f32|bf16 -> bf16)  =====================
__global__ void cvt1d_k(const void* __restrict__ src, bf16* __restrict__ dst,
                        int n, const int* __restrict__ flag)
{
  const int i = blockIdx.x * 256 + threadIdx.x;
  if (i < n)
    dst[i] = (*flag) ? (bf16)((const float*)src)[i] : ((const bf16*)src)[i];
}

// ========  weight transpose+normalize: (K x N) f32|bf16 -> (N x K) bf16  ======
// src element offset = (blockIdx.z + layer)*K*N ; dst offset = blockIdx.z*K*N
__global__ void wtrans_k(const void* __restrict__ src, bf16* __restrict__ dst,
                         int K, int N, int layer, const int* __restrict__ flag)
{
  __shared__ bf16 t[32][33];
  const size_t sOff = (size_t)(blockIdx.z + layer) * K * N;
  const size_t dOff = (size_t)blockIdx.z * K * N;
  const int n0 = blockIdx.x * 32, k0 = blockIdx.y * 32;
  const int tx = threadIdx.x, ty = threadIdx.y;   // (32,8)
  const int f = *flag;
#pragma unroll
  for (int i = 0; i < 4; i++) {
    const size_t idx = sOff + (size_t)(k0 + ty*4 + i) * N + n0 + tx;
    t[ty*4+i][tx] = f ? (bf16)((const float*)src)[idx] : ((const bf16*)src)[idx];
  }
  __syncthreads();
#pragma unroll
  for (int i = 0; i < 4; i++)
    dst[dOff + (size_t)(n0 + ty*4 + i) * K + k0 + tx] = t[tx][ty*4+i];
}

// =====================  MFMA GEMM, B^T (N x K) input  =====================
// C(MxN) = A(MxK) @ Bt(NxK)^T  [+ bias / residual / activation per EPI]
// EPI: 0 = fp32 raw (scores) ; 1 = bf16 (acc+bias)*scale ;
//      2 = fp32 acc+bias+res_bf16 ; 3 = bf16 gelu_exact(acc+bias) ;
//      4 = bf16 per-head transposed store -> vt[((b*NH+h)*DH+d)*SEQ+s]
// BMODE: 0 none ; 1 QK^T (A,B in BSHD; C chunk-local) ; 2 PV (A chunk-local probs)
template<int BM, int BN, int MT, int NT, int EPI, int BMODE>
__global__ __launch_bounds__(256)
void gemm_bt(const bf16* __restrict__ A, const bf16* __restrict__ Bt,
             float* __restrict__ Cf, bf16* __restrict__ Cb,
             const bf16* __restrict__ bias, const bf16* __restrict__ res,
             int K, int sA, int sB, int sC, float scale, int zbase)
{
  __shared__ __align__(16) bf16 ldsA[BM*32];
  __shared__ __align__(16) bf16 ldsB[BN*32];
  const int tid  = threadIdx.x;
  const int wave = tid >> 6;
  const int lane = tid & 63;
  const int quad = lane >> 4;
  const int l16  = lane & 15;
  const int wm = wave >> 1, wn = wave & 1;   // 2x2 wave grid

  size_t aOff = 0, bOff = 0, cOff = 0;
  if (BMODE == 1) {
    int z = (int)blockIdx.z + zbase;
    int b = z / NHEAD, h = z - b * NHEAD;
    aOff = (size_t)b * SEQ * HDIM + (size_t)h * DHEAD;
    bOff = aOff;
    cOff = (size_t)blockIdx.z * SEQ * SEQ;
  } else if (BMODE == 2) {
    int z = (int)blockIdx.z + zbase;
    int b = z / NHEAD, h = z - b * NHEAD;
    aOff = (size_t)blockIdx.z * SEQ * SEQ;
    bOff = (size_t)z * DHEAD * SEQ;
    cOff = (size_t)b * SEQ * HDIM + (size_t)h * DHEAD;
  }

  const int m0 = blockIdx.y * BM;
  const int n0 = blockIdx.x * BN;
  const int srow = tid >> 2;        // 0..63 (4 lanes per 32-elem row)
  const int scol = (tid & 3) * 8;

  const bf16* gA = A + aOff + (size_t)(m0 + srow) * sA + scol;
  const bf16* gB = Bt + bOff + (size_t)(n0 + srow) * sB + scol;
  bf16* lA = &ldsA[(wave * 16) * 32];
  bf16* lB = &ldsB[(wave * 16) * 32];

  f32x4 acc[MT][NT];
  const f32x4 fzero = {0.f, 0.f, 0.f, 0.f};
#pragma unroll
  for (int i = 0; i < MT; i++)
#pragma unroll
    for (int j = 0; j < NT; j++) acc[i][j] = fzero;

  for (int k0 = 0; k0 < K; k0 += 32) {
#pragma unroll
    for (int p = 0; p < BM/64; p++)
      async_copy16(gA + (size_t)p * 64 * sA + k0, lA + p * 64 * 32);
#pragma unroll
    for (int p = 0; p < BN/64; p++)
      async_copy16(gB + (size_t)p * 64 * sB + k0, lB + p * 64 * 32);
    __syncthreads();

    bf16x8 af[MT], bfv[NT];
#pragma unroll
    for (int i = 0; i < MT; i++)
      af[i] = *(const bf16x8*)&ldsA[(wm*(MT*16) + i*16 + l16) * 32 + quad*8];
#pragma unroll
    for (int j = 0; j < NT; j++)
      bfv[j] = *(const bf16x8*)&ldsB[(wn*(NT*16) + j*16 + l16) * 32 + quad*8];
#pragma unroll
    for (int i = 0; i < MT; i++)
#pragma unroll
      for (int j = 0; j < NT; j++)
        acc[i][j] = __builtin_amdgcn_mfma_f32_16x16x32_bf16(af[i], bfv[j], acc[i][j], 0, 0, 0);
    __syncthreads();
  }

  // ---- epilogue: C/D layout col=lane&15, row=quad*4+reg  [m89/m91 verified] ----
#pragma unroll
  for (int i = 0; i < MT; i++) {
    const int mtile = m0 + wm*(MT*16) + i*16 + quad*4;
#pragma unroll
    for (int j = 0; j < NT; j++) {
      const int nn = n0 + wn*(NT*16) + j*16 + l16;
      const float bv = bias ? (float)bias[nn] : 0.f;
      if (EPI == 4) {
        const int bb = mtile >> 9, s = mtile & 511;
        const int hh = nn >> 6, dd = nn & 63;
        const size_t base = ((size_t)(bb*NHEAD + hh) * DHEAD + dd) * SEQ + s;
        bf16x4 pk;
#pragma unroll
        for (int r = 0; r < 4; r++) pk[r] = (bf16)(acc[i][j][r] + bv);
        *(bf16x4*)(Cb + base) = pk;
      } else {
#pragma unroll
        for (int r = 0; r < 4; r++) {
          const int mm = mtile + r;
          const size_t idx = cOff + (size_t)mm * sC + nn;
          const float v = acc[i][j][r];
          if (EPI == 0) Cf[idx] = v;
          else if (EPI == 1) Cb[idx] = (bf16)((v + bv) * scale);
          else if (EPI == 2) Cf[idx] = v + bv + (float)res[(size_t)mm * sC + nn];
          else if (EPI == 3) {
            const float t = v + bv;
            Cb[idx] = (bf16)(0.5f * t * (1.0f + erff(t * 0.70710678118654752f)));
          }
        }
      }
    }
  }
}

// =====================  softmax over 512-length rows (fp32 -> bf16)  ==========
__global__ void softmax_k(const float* __restrict__ s, bf16* __restrict__ p)
{
  const int row  = blockIdx.x * 4 + (threadIdx.x >> 6);
  const int lane = threadIdx.x & 63;
  const float* sr = s + (size_t)row * SEQ;
  float v[8];
  float mx = -3.4e38f;
#pragma unroll
  for (int j = 0; j < 8; j++) { v[j] = sr[lane + 64*j]; mx = fmaxf(mx, v[j]); }
#pragma unroll
  for (int o = 32; o; o >>= 1) mx = fmaxf(mx, __shfl_xor(mx, o));
  float sum = 0.f;
#pragma unroll
  for (int j = 0; j < 8; j++) { v[j] = __expf(v[j] - mx); sum += v[j]; }
#pragma unroll
  for (int o = 32; o; o >>= 1) sum += __shfl_xor(sum, o);
  const float inv = 1.f / sum;
  bf16* pr = p + (size_t)row * SEQ;
#pragma unroll
  for (int j = 0; j < 8; j++) pr[lane + 64*j] = (bf16)(v[j] * inv);
}

// ========  LayerNorm over H=768, fp32 in, bf16 out (+ optional d_out)  ========
__global__ void layernorm_k(const float* __restrict__ x, const bf16* __restrict__ g,
                            const bf16* __restrict__ b, bf16* __restrict__ yb,
                            void* __restrict__ dout, int last, const int* __restrict__ flag)
{
  __shared__ float sred[4];
  const int row = blockIdx.x;
  const int tid = threadIdx.x;
  const float* xr = x + (size_t)row * HDIM;
  const float v0 = xr[tid], v1 = xr[tid+256], v2 = xr[tid+512];
  float s = v0 + v1 + v2;
#pragma unroll
  for (int o = 32; o; o >>= 1) s += __shfl_xor(s, o);
  if ((tid & 63) == 0) sred[tid >> 6] = s;
  __syncthreads();
  const float mean = (sred[0]+sred[1]+sred[2]+sred[3]) * (1.f/768.f);
  __syncthreads();
  const float d0 = v0-mean, d1 = v1-mean, d2 = v2-mean;
  float vs = d0*d0 + d1*d1 + d2*d2;
#pragma unroll
  for (int o = 32; o; o >>= 1) vs += __shfl_xor(vs, o);
  if ((tid & 63) == 0) sred[tid >> 6] = vs;
  __syncthreads();
  const float var = (sred[0]+sred[1]+sred[2]+sred[3]) * (1.f/768.f);
  const float rs  = rsqrtf(var + 1e-12f);
  const float y0 = d0*rs*(float)g[tid]     + (float)b[tid];
  const float y1 = d1*rs*(float)g[tid+256] + (float)b[tid+256];
  const float y2 = d2*rs*(float)g[tid+512] + (float)b[tid+512];
  bf16* ybr = yb + (size_t)row * HDIM;
  ybr[tid]     = (bf16)y0;
  ybr[tid+256] = (bf16)y1;
  ybr[tid+512] = (bf16)y2;
  if (last) {
    if (*flag) {
      float* o = (float*)dout + (size_t)row * HDIM;
      o[tid] = y0; o[tid+256] = y1; o[tid+512] = y2;
    } else {
      bf16* o = (bf16*)dout + (size_t)row * HDIM;
      o[tid] = (bf16)y0; o[tid+256] = (bf16)y1; o[tid+512] = (bf16)y2;
    }
  }
}

// ============================================================================
extern "C" void kernel_launch(void* const* d_in, const int* in_sizes, int n_in,
                              void* d_out, int out_size, void* d_ws, size_t ws_size,
                              hipStream_t stream)
{
  (void)in_sizes; (void)n_in; (void)out_size;

  // ---------------- adaptive workspace carve (pure function of ws_size) ------
  char* ws = (char*)d_ws;
  size_t off = 0;
  auto carve = [&](size_t bytes) -> char* {
    char* p = ws + off; off += (bytes + 255) & ~(size_t)255; return p;
  };
  int*   flag = (int*)carve(256);
  bf16*  hcur = (bf16*)carve((size_t)MTOK*HDIM*2);
  bf16*  qb   = (bf16*)carve((size_t)MTOK*HDIM*2);
  bf16*  kb   = (bf16*)carve((size_t)MTOK*HDIM*2);
  bf16*  vt   = (bf16*)carve((size_t)MTOK*HDIM*2);
  float* x1   = (float*)carve((size_t)MTOK*HDIM*4);
  bf16*  ctxb = qb;   // PV writes exactly the (b,h) slices its chunk's QK consumed
  bf16*  aob  = kb;   // kb dead once all attention chunks are done
  // normalized 1-D params
  bf16* nbq = (bf16*)carve((size_t)LNUM*HDIM*2);
  bf16* nbk = (bf16*)carve((size_t)LNUM*HDIM*2);
  bf16* nbv = (bf16*)carve((size_t)LNUM*HDIM*2);
  bf16* nbo = (bf16*)carve((size_t)LNUM*HDIM*2);
  bf16* ng1 = (bf16*)carve((size_t)LNUM*HDIM*2);
  bf16* nb1 = (bf16*)carve((size_t)LNUM*HDIM*2);
  bf16* nbi = (bf16*)carve((size_t)LNUM*IDIM*2);
  bf16* nbo2= (bf16*)carve((size_t)LNUM*HDIM*2);
  bf16* ng2 = (bf16*)carve((size_t)LNUM*HDIM*2);
  bf16* nb2 = (bf16*)carve((size_t)LNUM*HDIM*2);

  const size_t wAllBytes = 4ull*LNUM*HDIM*HDIM*2 + 2ull*LNUM*HDIM*IDIM*2; // ~84.9MB
  const bool preAll = ws_size >= off + wAllBytes + (size_t)4*SEQ*SEQ*6 + (1u<<20);
  bf16 *wqt=0,*wkt=0,*wvt=0,*wot=0,*wit=0,*wo2t=0,*bufA=0,*bufB=0;
  if (preAll) {
    wqt  = (bf16*)carve((size_t)LNUM*HDIM*HDIM*2);
    wkt  = (bf16*)carve((size_t)LNUM*HDIM*HDIM*2);
    wvt  = (bf16*)carve((size_t)LNUM*HDIM*HDIM*2);
    wot  = (bf16*)carve((size_t)LNUM*HDIM*HDIM*2);
    wit  = (bf16*)carve((size_t)LNUM*HDIM*IDIM*2);
    wo2t = (bf16*)carve((size_t)LNUM*HDIM*IDIM*2);
  } else {
    bufA = (bf16*)carve((size_t)HDIM*IDIM*2);   // holds any W^T (incl. Wi)
    bufB = (bf16*)carve((size_t)HDIM*IDIM*2);   // holds Wo2^T during FFN
  }

  const size_t unionAvail = (ws_size > off) ? (ws_size - off) : 0;
  int CH = 1;
  { const int chs[9] = {96,48,24,12,8,6,4,2,1};
    for (int i = 0; i < 9; i++)
      if ((size_t)chs[i]*SEQ*SEQ*6 <= unionAvail) { CH = chs[i]; break; } }
  int RM = 256;
  { const int rms[6] = {8192,4096,2048,1024,512,256};
    for (int i = 0; i < 6; i++)
      if ((size_t)rms[i]*IDIM*2 <= unionAvail) { RM = rms[i]; break; } }
  char*  uni     = ws + off;
  bf16*  interb  = (bf16*)uni;
  float* scoresC = (float*)uni;
  bf16*  probsC  = (bf16*)(uni + (size_t)CH*SEQ*SEQ*4);

  // ---------------- normalize inputs ----------------------------------------
  detect_k<<<1, 256, 0, stream>>>((const unsigned short*)d_in[1], flag);
  cvt1d_k<<<(MTOK*HDIM+255)/256, 256, 0, stream>>>(d_in[0], hcur, MTOK*HDIM, flag);
  cvt1d_k<<<(LNUM*HDIM+255)/256, 256, 0, stream>>>(d_in[2],  nbq,  LNUM*HDIM, flag);
  cvt1d_k<<<(LNUM*HDIM+255)/256, 256, 0, stream>>>(d_in[4],  nbk,  LNUM*HDIM, flag);
  cvt1d_k<<<(LNUM*HDIM+255)/256, 256, 0, stream>>>(d_in[6],  nbv,  LNUM*HDIM, flag);
  cvt1d_k<<<(LNUM*HDIM+255)/256, 256, 0, stream>>>(d_in[8],  nbo,  LNUM*HDIM, flag);
  cvt1d_k<<<(LNUM*HDIM+255)/256, 256, 0, stream>>>(d_in[9],  ng1,  LNUM*HDIM, flag);
  cvt1d_k<<<(LNUM*HDIM+255)/256, 256, 0, stream>>>(d_in[10], nb1,  LNUM*HDIM, flag);
  cvt1d_k<<<(LNUM*IDIM+255)/256, 256, 0, stream>>>(d_in[12], nbi,  LNUM*IDIM, flag);
  cvt1d_k<<<(LNUM*HDIM+255)/256, 256, 0, stream>>>(d_in[14], nbo2, LNUM*HDIM, flag);
  cvt1d_k<<<(LNUM*HDIM+255)/256, 256, 0, stream>>>(d_in[15], ng2,  LNUM*HDIM, flag);
  cvt1d_k<<<(LNUM*HDIM+255)/256, 256, 0, stream>>>(d_in[16], nb2,  LNUM*HDIM, flag);

  const dim3 tb(32, 8);
  if (preAll) {
    wtrans_k<<<dim3(HDIM/32, HDIM/32, LNUM), tb, 0, stream>>>(d_in[1],  wqt,  HDIM, HDIM, 0, flag);
    wtrans_k<<<dim3(HDIM/32, HDIM/32, LNUM), tb, 0, stream>>>(d_in[3],  wkt,  HDIM, HDIM, 0, flag);
    wtrans_k<<<dim3(HDIM/32, HDIM/32, LNUM), tb, 0, stream>>>(d_in[5],  wvt,  HDIM, HDIM, 0, flag);
    wtrans_k<<<dim3(HDIM/32, HDIM/32, LNUM), tb, 0, stream>>>(d_in[7],  wot,  HDIM, HDIM, 0, flag);
    wtrans_k<<<dim3(IDIM/32, HDIM/32, LNUM), tb, 0, stream>>>(d_in[11], wit,  HDIM, IDIM, 0, flag);
    wtrans_k<<<dim3(HDIM/32, IDIM/32, LNUM), tb, 0, stream>>>(d_in[13], wo2t, IDIM, HDIM, 0, flag);
  }
  // per-layer path: transpose+normalize layer l's weight right before use.
  auto getW = [&](const void* W, bf16* all, bf16* buf, int Kd, int Nd, int l) -> const bf16* {
    if (preAll) return all + (size_t)l * Kd * Nd;
    wtrans_k<<<dim3(Nd/32, Kd/32, 1), tb, 0, stream>>>(W, buf, Kd, Nd, l, flag);
    return buf;
  };

  for (int l = 0; l < LNUM; l++) {
    const bf16* hin = hcur;

    // q = (h@Wq + bq)/8 ; k = h@Wk + bk ; v^T per head
    const bf16* WqT = getW(d_in[1], wqt, bufA, HDIM, HDIM, l);
    gemm_bt<128,128,4,4,1,0><<<dim3(HDIM/128, MTOK/128), 256, 0, stream>>>(
        hin, WqT, nullptr, qb, nbq + l*HDIM, nullptr, HDIM, HDIM, HDIM, HDIM, 0.125f, 0);
    const bf16* WkT = getW(d_in[3], wkt, bufA, HDIM, HDIM, l);
    gemm_bt<128,128,4,4,1,0><<<dim3(HDIM/128, MTOK/128), 256, 0, stream>>>(
        hin, WkT, nullptr, kb, nbk + l*HDIM, nullptr, HDIM, HDIM, HDIM, HDIM, 1.f, 0);
    const bf16* WvT = getW(d_in[5], wvt, bufA, HDIM, HDIM, l);
    gemm_bt<128,128,4,4,4,0><<<dim3(HDIM/128, MTOK/128), 256, 0, stream>>>(
        hin, WvT, nullptr, vt, nbv + l*HDIM, nullptr, HDIM, HDIM, HDIM, SEQ, 1.f, 0);

    // attention in chunks of CH (b,h) pairs
    for (int c = 0; c < (NB*NHEAD)/CH; c++) {
      const int zb = c * CH;
      gemm_bt<128,128,4,4,0,1><<<dim3(SEQ/128, SEQ/128, CH), 256, 0, stream>>>(
          qb, kb, scoresC, nullptr, nullptr, nullptr, DHEAD, HDIM, HDIM, SEQ, 1.f, zb);
      softmax_k<<<CH*SEQ/4, 256, 0, stream>>>(scoresC, probsC);
      gemm_bt<128,64,4,2,1,2><<<dim3(1, SEQ/128, CH), 256, 0, stream>>>(
          probsC, vt, nullptr, ctxb, nullptr, nullptr, SEQ, SEQ, SEQ, HDIM, 1.f, zb);
    }

    // x1 = ctx@Wo + bo + h ; attn_out = LN(x1) -> aob
    const bf16* WoT = getW(d_in[7], wot, bufA, HDIM, HDIM, l);
    gemm_bt<128,128,4,4,2,0><<<dim3(HDIM/128, MTOK/128), 256, 0, stream>>>(
        ctxb, WoT, x1, nullptr, nbo + l*HDIM, hin, HDIM, HDIM, HDIM, HDIM, 1.f, 0);
    layernorm_k<<<MTOK, 256, 0, stream>>>(x1, ng1 + l*HDIM, nb1 + l*HDIM, aob,
                                          d_out, 0, flag);

    // FFN in row-chunks of RM
    const bf16* WiT  = getW(d_in[11], wit,  bufA, HDIM, IDIM, l);
    const bf16* Wo2T = getW(d_in[13], wo2t, bufB, IDIM, HDIM, l);
    for (int r0 = 0; r0 < MTOK; r0 += RM) {
      gemm_bt<128,128,4,4,3,0><<<dim3(IDIM/128, RM/128), 256, 0, stream>>>(
          aob + (size_t)r0*HDIM, WiT, nullptr, interb, nbi + l*IDIM, nullptr,
          HDIM, HDIM, HDIM, IDIM, 1.f, 0);
      gemm_bt<128,128,4,4,2,0><<<dim3(HDIM/128, RM/128), 256, 0, stream>>>(
          interb, Wo2T, x1 + (size_t)r0*HDIM, nullptr, nbo2 + l*HDIM,
          aob + (size_t)r0*HDIM, IDIM, IDIM, IDIM, HDIM, 1.f, 0);
    }
    layernorm_k<<<MTOK, 256, 0, stream>>>(x1, ng2 + l*HDIM, nb2 + l*HDIM, hcur,
                                          d_out, (l == LNUM-1) ? 1 : 0, flag);
  }
}

// Round 4
// 2157.870 us; speedup vs baseline: 1.3720x; 1.3720x over previous
//
#include <hip/hip_runtime.h>
#include <hip/hip_bf16.h>
#include <math.h>

#define LNUM  6
#define HDIM  768
#define NHEAD 12
#define DHEAD 64
#define IDIM  3072
#define NB    16
#define SEQ   512
#define MTOK  (NB*SEQ)   // 8192
#define NQKV  (3*HDIM)   // 2304

typedef __bf16 bf16;
typedef __bf16 bf16x4 __attribute__((ext_vector_type(4)));
typedef __bf16 bf16x8 __attribute__((ext_vector_type(8)));
typedef float  f32x4  __attribute__((ext_vector_type(4)));

__device__ __forceinline__ void async_copy16(const bf16* g, bf16* l) {
  __builtin_amdgcn_global_load_lds((__attribute__((address_space(1))) void*)g,
                                   (__attribute__((address_space(3))) void*)l,
                                   16, 0, 0);
}

// =====================  dtype detector (f32 vs bf16 input)  ==================
__global__ void detect_k(const unsigned short* __restrict__ probe, int* __restrict__ flag)
{
  __shared__ int sc[4];
  const int tid = threadIdx.x;
  int cnt = 0;
#pragma unroll
  for (int j = 0; j < 16; j++) {
    const unsigned short w = probe[tid * 16 + j];
    const int e = (w >> 7) & 0xFF;
    cnt += (e >= 90 && e <= 130) ? 1 : 0;
  }
#pragma unroll
  for (int o = 32; o; o >>= 1) cnt += __shfl_xor(cnt, o);
  if ((tid & 63) == 0) sc[tid >> 6] = cnt;
  __syncthreads();
  if (tid == 0) flag[0] = ((sc[0] + sc[1] + sc[2] + sc[3]) < 3482) ? 1 : 0;
}

// =====================  normalize copies  =====================
__global__ void cvt1d_k(const void* __restrict__ src, bf16* __restrict__ dst,
                        int n, const int* __restrict__ flag)
{
  const int i = blockIdx.x * 256 + threadIdx.x;
  if (i < n)
    dst[i] = (*flag) ? (bf16)((const float*)src)[i] : ((const bf16*)src)[i];
}

// slice-copy [L][perL] -> dst[l*dstStride + off + c]   (for qkv bias concat)
__global__ void cvt_slice_k(const void* __restrict__ src, bf16* __restrict__ dst,
                            int perL, int off, int dstStride, int total,
                            const int* __restrict__ flag)
{
  const int i = blockIdx.x * 256 + threadIdx.x;
  if (i < total) {
    const int l = i / perL, c = i - l * perL;
    const bf16 v = (*flag) ? (bf16)((const float*)src)[i] : ((const bf16*)src)[i];
    dst[l * dstStride + off + c] = v;
  }
}

// ====  weight transpose+normalize: (K x N) -> (N x K) bf16, strided dst  =====
// src elem offset = (z+layer)*K*N ; dst = z*dstLS + dstOff + n*K + k
__global__ void wtrans_k(const void* __restrict__ src, bf16* __restrict__ dst,
                         int K, int N, int layer, int dstLS, int dstOff,
                         const int* __restrict__ flag)
{
  __shared__ bf16 t[32][33];
  const size_t sOff = (size_t)(blockIdx.z + layer) * K * N;
  const size_t dOff = (size_t)blockIdx.z * dstLS + dstOff;
  const int n0 = blockIdx.x * 32, k0 = blockIdx.y * 32;
  const int tx = threadIdx.x, ty = threadIdx.y;   // (32,8)
  const int f = *flag;
#pragma unroll
  for (int i = 0; i < 4; i++) {
    const size_t idx = sOff + (size_t)(k0 + ty*4 + i) * N + n0 + tx;
    t[ty*4+i][tx] = f ? (bf16)((const float*)src)[idx] : ((const bf16*)src)[idx];
  }
  __syncthreads();
#pragma unroll
  for (int i = 0; i < 4; i++)
    dst[dOff + (size_t)(n0 + ty*4 + i) * K + k0 + tx] = t[tx][ty*4+i];
}

// =====================  MFMA GEMM, B^T (N x K) input  =====================
// EPI: 2 = fp32 acc+bias+res_bf16 -> Cf
//      3 = bf16 gelu_exact(acc+bias) -> Cb
//      5 = fused QKV routing: nn<768 -> Cb=q (*0.125); <1536 -> Cb2=k;
//          else Cb3 = v^T per-head [((b*NH+h)*DH+d)*SEQ+s]
// XS: 1 = XCD-aware block swizzle (requires gridDim.y % 8 == 0)
template<int BM, int BN, int MT, int NT, int EPI, int XS>
__global__ __launch_bounds__(256)
void gemm_bt(const bf16* __restrict__ A, const bf16* __restrict__ Bt,
             float* __restrict__ Cf, bf16* __restrict__ Cb,
             bf16* __restrict__ Cb2, bf16* __restrict__ Cb3,
             const bf16* __restrict__ bias, const bf16* __restrict__ res,
             int K, int sA, int sB, int sC)
{
  __shared__ __align__(16) bf16 ldsA[BM*32];
  __shared__ __align__(16) bf16 ldsB[BN*32];
  const int tid  = threadIdx.x;
  const int wave = tid >> 6;
  const int lane = tid & 63;
  const int quad = lane >> 4;
  const int l16  = lane & 15;
  const int wm = wave >> 1, wn = wave & 1;   // 2x2 wave grid

  int bx = blockIdx.x, by = blockIdx.y;
  if (XS) {
    if ((gridDim.y & 7) == 0) {
      const int id  = by * gridDim.x + bx;
      const int xcd = id & 7, slot = id >> 3;
      bx = slot % gridDim.x;
      by = (slot / gridDim.x) * 8 + xcd;
    }
  }
  const int m0 = by * BM;
  const int n0 = bx * BN;
  const int srow = tid >> 2;
  const int scol = (tid & 3) * 8;

  const bf16* gA = A + (size_t)(m0 + srow) * sA + scol;
  const bf16* gB = Bt + (size_t)(n0 + srow) * sB + scol;
  bf16* lA = &ldsA[(wave * 16) * 32];
  bf16* lB = &ldsB[(wave * 16) * 32];

  f32x4 acc[MT][NT];
  const f32x4 fzero = {0.f, 0.f, 0.f, 0.f};
#pragma unroll
  for (int i = 0; i < MT; i++)
#pragma unroll
    for (int j = 0; j < NT; j++) acc[i][j] = fzero;

  for (int k0 = 0; k0 < K; k0 += 32) {
#pragma unroll
    for (int p = 0; p < BM/64; p++)
      async_copy16(gA + (size_t)p * 64 * sA + k0, lA + p * 64 * 32);
#pragma unroll
    for (int p = 0; p < BN/64; p++)
      async_copy16(gB + (size_t)p * 64 * sB + k0, lB + p * 64 * 32);
    __syncthreads();

    bf16x8 af[MT], bfv[NT];
#pragma unroll
    for (int i = 0; i < MT; i++)
      af[i] = *(const bf16x8*)&ldsA[(wm*(MT*16) + i*16 + l16) * 32 + quad*8];
#pragma unroll
    for (int j = 0; j < NT; j++)
      bfv[j] = *(const bf16x8*)&ldsB[(wn*(NT*16) + j*16 + l16) * 32 + quad*8];
#pragma unroll
    for (int i = 0; i < MT; i++)
#pragma unroll
      for (int j = 0; j < NT; j++)
        acc[i][j] = __builtin_amdgcn_mfma_f32_16x16x32_bf16(af[i], bfv[j], acc[i][j], 0, 0, 0);
    __syncthreads();
  }

  // epilogue: C/D layout col=lane&15, row=quad*4+reg
#pragma unroll
  for (int i = 0; i < MT; i++) {
    const int mtile = m0 + wm*(MT*16) + i*16 + quad*4;
#pragma unroll
    for (int j = 0; j < NT; j++) {
      const int nn = n0 + wn*(NT*16) + j*16 + l16;
      const float bv = bias ? (float)bias[nn] : 0.f;
      if (EPI == 5) {
        if (nn < HDIM) {
#pragma unroll
          for (int r = 0; r < 4; r++)
            Cb[(size_t)(mtile + r) * HDIM + nn] = (bf16)((acc[i][j][r] + bv) * 0.125f);
        } else if (nn < 2*HDIM) {
#pragma unroll
          for (int r = 0; r < 4; r++)
            Cb2[(size_t)(mtile + r) * HDIM + (nn - HDIM)] = (bf16)(acc[i][j][r] + bv);
        } else {
          const int nn2 = nn - 2*HDIM;
          const int bb = mtile >> 9, s = mtile & 511;
          const int hh = nn2 >> 6, dd = nn2 & 63;
          const size_t base = ((size_t)(bb*NHEAD + hh) * DHEAD + dd) * SEQ + s;
          bf16x4 pk;
#pragma unroll
          for (int r = 0; r < 4; r++) pk[r] = (bf16)(acc[i][j][r] + bv);
          *(bf16x4*)(Cb3 + base) = pk;
        }
      } else {
#pragma unroll
        for (int r = 0; r < 4; r++) {
          const int mm = mtile + r;
          const size_t idx = (size_t)mm * sC + nn;
          const float v = acc[i][j][r];
          if (EPI == 2) Cf[idx] = v + bv + (float)res[idx];
          else if (EPI == 3) {
            const float t = v + bv;
            Cb[idx] = (bf16)(0.5f * t * (1.0f + erff(t * 0.70710678118654752f)));
          }
        }
      }
    }
  }
}

// =====================  fused flash attention  =====================
// grid (4 q-tiles, 192 bh), 256 threads (4 waves), Q-tile 128, KV-tile 64.
// q pre-scaled by 1/8. kb: [b*512+s][768] head cols. vt: [(z*64+d)*512+s].
__global__ __launch_bounds__(256)
void flash_k(const bf16* __restrict__ qb, const bf16* __restrict__ kb,
             const bf16* __restrict__ vt, bf16* __restrict__ ctxb)
{
  __shared__ __align__(16) bf16 Qs[128][72];
  __shared__ __align__(16) bf16 Ks[64][72];
  __shared__ __align__(16) bf16 Vs[64][72];
  __shared__ __align__(16) bf16 Ps[128][72];
  const int tid = threadIdx.x;
  const int wave = tid >> 6, lane = tid & 63;
  const int quad = lane >> 4, l16 = lane & 15;
  const int z = blockIdx.y;
  const int b = z / NHEAD, h = z - b * NHEAD;
  const int qt = blockIdx.x;
  const size_t qRow0 = (size_t)b * SEQ + qt * 128;

  // stage Q once (128 x 64)
#pragma unroll
  for (int r = 0; r < 4; r++) {
    const int idx = tid + r * 256;
    const int row = idx >> 3, c8 = (idx & 7) * 8;
    *(bf16x8*)&Qs[row][c8] =
        *(const bf16x8*)&qb[(qRow0 + row) * HDIM + h * DHEAD + c8];
  }

  f32x4 Oacc[2][4];
  float mrow[2][4], lrow[2][4];
#pragma unroll
  for (int i = 0; i < 2; i++)
#pragma unroll
    for (int n = 0; n < 4; n++) Oacc[i][n] = (f32x4){0.f,0.f,0.f,0.f};
#pragma unroll
  for (int i = 0; i < 2; i++)
#pragma unroll
    for (int r = 0; r < 4; r++) { mrow[i][r] = -3.0e38f; lrow[i][r] = 0.f; }

  for (int j = 0; j < 8; j++) {
    __syncthreads();   // protect Ks/Vs/Ps from overwrite while prior iter reads
#pragma unroll
    for (int r = 0; r < 2; r++) {
      const int idx = tid + r * 256;
      const int row = idx >> 3, c8 = (idx & 7) * 8;
      *(bf16x8*)&Ks[row][c8] =
          *(const bf16x8*)&kb[((size_t)b*SEQ + j*64 + row) * HDIM + h*DHEAD + c8];
      *(bf16x8*)&Vs[row][c8] =
          *(const bf16x8*)&vt[((size_t)z*DHEAD + row) * SEQ + j*64 + c8];
    }
    __syncthreads();

    // S = Q K^T  (wave handles rows wave*32..+31; cols 0..63)
    f32x4 Sacc[2][4];
#pragma unroll
    for (int i = 0; i < 2; i++)
#pragma unroll
      for (int n = 0; n < 4; n++) Sacc[i][n] = (f32x4){0.f,0.f,0.f,0.f};
#pragma unroll
    for (int kk = 0; kk < 2; kk++) {
      bf16x8 af[2], bv[4];
#pragma unroll
      for (int i = 0; i < 2; i++)
        af[i] = *(const bf16x8*)&Qs[wave*32 + i*16 + l16][kk*32 + quad*8];
#pragma unroll
      for (int n = 0; n < 4; n++)
        bv[n] = *(const bf16x8*)&Ks[n*16 + l16][kk*32 + quad*8];
#pragma unroll
      for (int i = 0; i < 2; i++)
#pragma unroll
        for (int n = 0; n < 4; n++)
          Sacc[i][n] = __builtin_amdgcn_mfma_f32_16x16x32_bf16(af[i], bv[n], Sacc[i][n], 0,0,0);
    }

    // online softmax stats (row = wave*32 + i*16 + quad*4 + r)
    float alpha[2][4];
#pragma unroll
    for (int i = 0; i < 2; i++)
#pragma unroll
      for (int r = 0; r < 4; r++) {
        float mx = Sacc[i][0][r];
#pragma unroll
        for (int n = 1; n < 4; n++) mx = fmaxf(mx, Sacc[i][n][r]);
#pragma unroll
        for (int o = 8; o; o >>= 1) mx = fmaxf(mx, __shfl_xor(mx, o));
        const float mn = fmaxf(mrow[i][r], mx);
        const float a = __expf(mrow[i][r] - mn);
        float rs = 0.f;
#pragma unroll
        for (int n = 0; n < 4; n++) {
          const float p = __expf(Sacc[i][n][r] - mn);
          Sacc[i][n][r] = p; rs += p;
        }
#pragma unroll
        for (int o = 8; o; o >>= 1) rs += __shfl_xor(rs, o);
        lrow[i][r] = lrow[i][r] * a + rs;
        mrow[i][r] = mn;
        alpha[i][r] = a;
      }

    // P -> LDS in A-operand layout [m][kv]
#pragma unroll
    for (int i = 0; i < 2; i++)
#pragma unroll
      for (int n = 0; n < 4; n++)
#pragma unroll
        for (int r = 0; r < 4; r++)
          Ps[wave*32 + i*16 + quad*4 + r][n*16 + l16] = (bf16)Sacc[i][n][r];
    __syncthreads();

    // O = O*alpha + P V
#pragma unroll
    for (int i = 0; i < 2; i++)
#pragma unroll
      for (int n = 0; n < 4; n++)
#pragma unroll
        for (int r = 0; r < 4; r++) Oacc[i][n][r] *= alpha[i][r];
#pragma unroll
    for (int kk = 0; kk < 2; kk++) {
      bf16x8 af[2], bv[4];
#pragma unroll
      for (int i = 0; i < 2; i++)
        af[i] = *(const bf16x8*)&Ps[wave*32 + i*16 + l16][kk*32 + quad*8];
#pragma unroll
      for (int n = 0; n < 4; n++)
        bv[n] = *(const bf16x8*)&Vs[n*16 + l16][kk*32 + quad*8];
#pragma unroll
      for (int i = 0; i < 2; i++)
#pragma unroll
        for (int n = 0; n < 4; n++)
          Oacc[i][n] = __builtin_amdgcn_mfma_f32_16x16x32_bf16(af[i], bv[n], Oacc[i][n], 0,0,0);
    }
  }

  // epilogue: ctx[token][h*64+d] = O / l
#pragma unroll
  for (int i = 0; i < 2; i++)
#pragma unroll
    for (int r = 0; r < 4; r++) {
      const float inv = 1.f / lrow[i][r];
      const size_t tok = qRow0 + wave*32 + i*16 + quad*4 + r;
#pragma unroll
      for (int n = 0; n < 4; n++)
        ctxb[tok * HDIM + h*DHEAD + n*16 + l16] = (bf16)(Oacc[i][n][r] * inv);
    }
}

// ========  LayerNorm over H=768, fp32 in, bf16 out (+ optional d_out)  ========
__global__ void layernorm_k(const float* __restrict__ x, const bf16* __restrict__ g,
                            const bf16* __restrict__ b, bf16* __restrict__ yb,
                            void* __restrict__ dout, int last, const int* __restrict__ flag)
{
  __shared__ float sred[4];
  const int row = blockIdx.x;
  const int tid = threadIdx.x;
  const float* xr = x + (size_t)row * HDIM;
  const float v0 = xr[tid], v1 = xr[tid+256], v2 = xr[tid+512];
  float s = v0 + v1 + v2;
#pragma unroll
  for (int o = 32; o; o >>= 1) s += __shfl_xor(s, o);
  if ((tid & 63) == 0) sred[tid >> 6] = s;
  __syncthreads();
  const float mean = (sred[0]+sred[1]+sred[2]+sred[3]) * (1.f/768.f);
  __syncthreads();
  const float d0 = v0-mean, d1 = v1-mean, d2 = v2-mean;
  float vs = d0*d0 + d1*d1 + d2*d2;
#pragma unroll
  for (int o = 32; o; o >>= 1) vs += __shfl_xor(vs, o);
  if ((tid & 63) == 0) sred[tid >> 6] = vs;
  __syncthreads();
  const float var = (sred[0]+sred[1]+sred[2]+sred[3]) * (1.f/768.f);
  const float rs  = rsqrtf(var + 1e-12f);
  const float y0 = d0*rs*(float)g[tid]     + (float)b[tid];
  const float y1 = d1*rs*(float)g[tid+256] + (float)b[tid+256];
  const float y2 = d2*rs*(float)g[tid+512] + (float)b[tid+512];
  bf16* ybr = yb + (size_t)row * HDIM;
  ybr[tid]     = (bf16)y0;
  ybr[tid+256] = (bf16)y1;
  ybr[tid+512] = (bf16)y2;
  if (last) {
    if (*flag) {
      float* o = (float*)dout + (size_t)row * HDIM;
      o[tid] = y0; o[tid+256] = y1; o[tid+512] = y2;
    } else {
      bf16* o = (bf16*)dout + (size_t)row * HDIM;
      o[tid] = (bf16)y0; o[tid+256] = (bf16)y1; o[tid+512] = (bf16)y2;
    }
  }
}

// ============================================================================
extern "C" void kernel_launch(void* const* d_in, const int* in_sizes, int n_in,
                              void* d_out, int out_size, void* d_ws, size_t ws_size,
                              hipStream_t stream)
{
  (void)in_sizes; (void)n_in; (void)out_size;

  char* ws = (char*)d_ws;
  size_t off = 0;
  auto carve = [&](size_t bytes) -> char* {
    char* p = ws + off; off += (bytes + 255) & ~(size_t)255; return p;
  };
  int*   flag = (int*)carve(256);
  bf16*  hcur = (bf16*)carve((size_t)MTOK*HDIM*2);
  bf16*  qb   = (bf16*)carve((size_t)MTOK*HDIM*2);
  bf16*  kb   = (bf16*)carve((size_t)MTOK*HDIM*2);
  bf16*  vt   = (bf16*)carve((size_t)MTOK*HDIM*2);
  bf16*  ctxb = (bf16*)carve((size_t)MTOK*HDIM*2);
  float* x1   = (float*)carve((size_t)MTOK*HDIM*4);
  bf16*  aob  = kb;   // kb dead once flash attention of the layer is complete

  bf16* nbqkv = (bf16*)carve((size_t)LNUM*NQKV*2);
  bf16* nbo   = (bf16*)carve((size_t)LNUM*HDIM*2);
  bf16* ng1   = (bf16*)carve((size_t)LNUM*HDIM*2);
  bf16* nb1   = (bf16*)carve((size_t)LNUM*HDIM*2);
  bf16* nbi   = (bf16*)carve((size_t)LNUM*IDIM*2);
  bf16* nbo2  = (bf16*)carve((size_t)LNUM*HDIM*2);
  bf16* ng2   = (bf16*)carve((size_t)LNUM*HDIM*2);
  bf16* nb2   = (bf16*)carve((size_t)LNUM*HDIM*2);

  const size_t wAllBytes = (size_t)LNUM*(NQKV*HDIM + HDIM*HDIM + 2*HDIM*IDIM)*2; // ~84.9MB
  const bool preAll = ws_size >= off + wAllBytes + (size_t)256*IDIM*2 + (1u<<20);
  bf16 *wqkvt=0, *wot=0, *wit=0, *wo2t=0, *bufA=0, *bufB=0;
  if (preAll) {
    wqkvt = (bf16*)carve((size_t)LNUM*NQKV*HDIM*2);
    wot   = (bf16*)carve((size_t)LNUM*HDIM*HDIM*2);
    wit   = (bf16*)carve((size_t)LNUM*HDIM*IDIM*2);
    wo2t  = (bf16*)carve((size_t)LNUM*HDIM*IDIM*2);
  } else {
    bufA = (bf16*)carve((size_t)HDIM*IDIM*2);   // any W^T (incl. 2304x768 QKV)
    bufB = (bf16*)carve((size_t)HDIM*IDIM*2);   // Wo2^T during FFN
  }

  const size_t unionAvail = (ws_size > off) ? (ws_size - off) : 0;
  int RM = 256;
  { const int rms[6] = {8192,4096,2048,1024,512,256};
    for (int i = 0; i < 6; i++)
      if ((size_t)rms[i]*IDIM*2 <= unionAvail) { RM = rms[i]; break; } }
  bf16* interb = (bf16*)(ws + off);

  // ---------------- normalize inputs ----------------------------------------
  detect_k<<<1, 256, 0, stream>>>((const unsigned short*)d_in[1], flag);
  cvt1d_k<<<(MTOK*HDIM+255)/256, 256, 0, stream>>>(d_in[0], hcur, MTOK*HDIM, flag);
  cvt_slice_k<<<(LNUM*HDIM+255)/256, 256, 0, stream>>>(d_in[2], nbqkv, HDIM, 0,      NQKV, LNUM*HDIM, flag);
  cvt_slice_k<<<(LNUM*HDIM+255)/256, 256, 0, stream>>>(d_in[4], nbqkv, HDIM, HDIM,   NQKV, LNUM*HDIM, flag);
  cvt_slice_k<<<(LNUM*HDIM+255)/256, 256, 0, stream>>>(d_in[6], nbqkv, HDIM, 2*HDIM, NQKV, LNUM*HDIM, flag);
  cvt1d_k<<<(LNUM*HDIM+255)/256, 256, 0, stream>>>(d_in[8],  nbo,  LNUM*HDIM, flag);
  cvt1d_k<<<(LNUM*HDIM+255)/256, 256, 0, stream>>>(d_in[9],  ng1,  LNUM*HDIM, flag);
  cvt1d_k<<<(LNUM*HDIM+255)/256, 256, 0, stream>>>(d_in[10], nb1,  LNUM*HDIM, flag);
  cvt1d_k<<<(LNUM*IDIM+255)/256, 256, 0, stream>>>(d_in[12], nbi,  LNUM*IDIM, flag);
  cvt1d_k<<<(LNUM*HDIM+255)/256, 256, 0, stream>>>(d_in[14], nbo2, LNUM*HDIM, flag);
  cvt1d_k<<<(LNUM*HDIM+255)/256, 256, 0, stream>>>(d_in[15], ng2,  LNUM*HDIM, flag);
  cvt1d_k<<<(LNUM*HDIM+255)/256, 256, 0, stream>>>(d_in[16], nb2,  LNUM*HDIM, flag);

  const dim3 tb(32, 8);
  if (preAll) {
    wtrans_k<<<dim3(HDIM/32, HDIM/32, LNUM), tb, 0, stream>>>(d_in[1], wqkvt, HDIM, HDIM, 0, NQKV*HDIM, 0,           flag);
    wtrans_k<<<dim3(HDIM/32, HDIM/32, LNUM), tb, 0, stream>>>(d_in[3], wqkvt, HDIM, HDIM, 0, NQKV*HDIM, HDIM*HDIM,   flag);
    wtrans_k<<<dim3(HDIM/32, HDIM/32, LNUM), tb, 0, stream>>>(d_in[5], wqkvt, HDIM, HDIM, 0, NQKV*HDIM, 2*HDIM*HDIM, flag);
    wtrans_k<<<dim3(HDIM/32, HDIM/32, LNUM), tb, 0, stream>>>(d_in[7], wot,  HDIM, HDIM, 0, HDIM*HDIM, 0, flag);
    wtrans_k<<<dim3(IDIM/32, HDIM/32, LNUM), tb, 0, stream>>>(d_in[11], wit,  HDIM, IDIM, 0, HDIM*IDIM, 0, flag);
    wtrans_k<<<dim3(HDIM/32, IDIM/32, LNUM), tb, 0, stream>>>(d_in[13], wo2t, IDIM, HDIM, 0, HDIM*IDIM, 0, flag);
  }

  for (int l = 0; l < LNUM; l++) {
    const bf16* hin = hcur;

    // ---- fused QKV ----
    const bf16* WqkvT;
    if (preAll) WqkvT = wqkvt + (size_t)l * NQKV * HDIM;
    else {
      wtrans_k<<<dim3(HDIM/32, HDIM/32, 1), tb, 0, stream>>>(d_in[1], bufA, HDIM, HDIM, l, 0, 0,           flag);
      wtrans_k<<<dim3(HDIM/32, HDIM/32, 1), tb, 0, stream>>>(d_in[3], bufA, HDIM, HDIM, l, 0, HDIM*HDIM,   flag);
      wtrans_k<<<dim3(HDIM/32, HDIM/32, 1), tb, 0, stream>>>(d_in[5], bufA, HDIM, HDIM, l, 0, 2*HDIM*HDIM, flag);
      WqkvT = bufA;
    }
    gemm_bt<128,128,4,4,5,1><<<dim3(NQKV/128, MTOK/128), 256, 0, stream>>>(
        hin, WqkvT, nullptr, qb, kb, vt, nbqkv + (size_t)l*NQKV, nullptr,
        HDIM, HDIM, HDIM, HDIM);

    // ---- fused flash attention ----
    flash_k<<<dim3(SEQ/128, NB*NHEAD), 256, 0, stream>>>(qb, kb, vt, ctxb);

    // ---- x1 = ctx@Wo + bo + h ; attn_out = LN(x1) -> aob ----
    const bf16* WoT;
    if (preAll) WoT = wot + (size_t)l * HDIM * HDIM;
    else {
      wtrans_k<<<dim3(HDIM/32, HDIM/32, 1), tb, 0, stream>>>(d_in[7], bufA, HDIM, HDIM, l, 0, 0, flag);
      WoT = bufA;
    }
    gemm_bt<128,128,4,4,2,1><<<dim3(HDIM/128, MTOK/128), 256, 0, stream>>>(
        ctxb, WoT, x1, nullptr, nullptr, nullptr, nbo + l*HDIM, hin,
        HDIM, HDIM, HDIM, HDIM);
    layernorm_k<<<MTOK, 256, 0, stream>>>(x1, ng1 + l*HDIM, nb1 + l*HDIM, aob,
                                          d_out, 0, flag);

    // ---- FFN ----
    const bf16 *WiT, *Wo2T;
    if (preAll) { WiT = wit + (size_t)l*HDIM*IDIM; Wo2T = wo2t + (size_t)l*HDIM*IDIM; }
    else {
      wtrans_k<<<dim3(IDIM/32, HDIM/32, 1), tb, 0, stream>>>(d_in[11], bufA, HDIM, IDIM, l, 0, 0, flag);
      wtrans_k<<<dim3(HDIM/32, IDIM/32, 1), tb, 0, stream>>>(d_in[13], bufB, IDIM, HDIM, l, 0, 0, flag);
      WiT = bufA; Wo2T = bufB;
    }
    for (int r0 = 0; r0 < MTOK; r0 += RM) {
      gemm_bt<128,128,4,4,3,1><<<dim3(IDIM/128, RM/128), 256, 0, stream>>>(
          aob + (size_t)r0*HDIM, WiT, nullptr, interb, nullptr, nullptr,
          nbi + (size_t)l*IDIM, nullptr, HDIM, HDIM, HDIM, IDIM);
      gemm_bt<128,128,4,4,2,1><<<dim3(HDIM/128, RM/128), 256, 0, stream>>>(
          interb, Wo2T, x1 + (size_t)r0*HDIM, nullptr, nullptr, nullptr,
          nbo2 + l*HDIM, aob + (size_t)r0*HDIM, IDIM, IDIM, IDIM, HDIM);
    }
    layernorm_k<<<MTOK, 256, 0, stream>>>(x1, ng2 + l*HDIM, nb2 + l*HDIM, hcur,
                                          d_out, (l == LNUM-1) ? 1 : 0, flag);
  }
}

// Round 5
// 2081.602 us; speedup vs baseline: 1.4223x; 1.0366x over previous
//
#include <hip/hip_runtime.h>
#include <hip/hip_bf16.h>
#include <math.h>

#define LNUM  6
#define HDIM  768
#define NHEAD 12
#define DHEAD 64
#define IDIM  3072
#define NB    16
#define SEQ   512
#define MTOK  (NB*SEQ)   // 8192
#define NQKV  (3*HDIM)   // 2304

typedef __bf16 bf16;
typedef __bf16 bf16x4 __attribute__((ext_vector_type(4)));
typedef __bf16 bf16x8 __attribute__((ext_vector_type(8)));
typedef float  f32x4  __attribute__((ext_vector_type(4)));

__device__ __forceinline__ void async_copy16(const bf16* g, bf16* l) {
  __builtin_amdgcn_global_load_lds((__attribute__((address_space(1))) void*)g,
                                   (__attribute__((address_space(3))) void*)l,
                                   16, 0, 0);
}

// fast gelu (tanh form): max abs err vs exact-erf gelu ~3e-3
__device__ __forceinline__ float gelu_fast(float t) {
  const float u = 0.7978845608f * (t + 0.044715f * t * t * t);
  const float e = __expf(-2.f * fabsf(u));
  const float th = (1.f - e) / (1.f + e);
  return 0.5f * t * (1.f + copysignf(th, u));
}

// =====================  dtype detector (f32 vs bf16 input)  ==================
__global__ void detect_k(const unsigned short* __restrict__ probe, int* __restrict__ flag)
{
  __shared__ int sc[4];
  const int tid = threadIdx.x;
  int cnt = 0;
#pragma unroll
  for (int j = 0; j < 16; j++) {
    const unsigned short w = probe[tid * 16 + j];
    const int e = (w >> 7) & 0xFF;
    cnt += (e >= 90 && e <= 130) ? 1 : 0;
  }
#pragma unroll
  for (int o = 32; o; o >>= 1) cnt += __shfl_xor(cnt, o);
  if ((tid & 63) == 0) sc[tid >> 6] = cnt;
  __syncthreads();
  if (tid == 0) flag[0] = ((sc[0] + sc[1] + sc[2] + sc[3]) < 3482) ? 1 : 0;
}

// =====================  normalize copies  =====================
__global__ void cvt1d_k(const void* __restrict__ src, bf16* __restrict__ dst,
                        int n, const int* __restrict__ flag)
{
  const int i = blockIdx.x * 256 + threadIdx.x;
  if (i < n)
    dst[i] = (*flag) ? (bf16)((const float*)src)[i] : ((const bf16*)src)[i];
}

// slice-copy [L][perL] -> dst[l*dstStride + off + c]   (for qkv bias concat)
__global__ void cvt_slice_k(const void* __restrict__ src, bf16* __restrict__ dst,
                            int perL, int off, int dstStride, int total,
                            const int* __restrict__ flag)
{
  const int i = blockIdx.x * 256 + threadIdx.x;
  if (i < total) {
    const int l = i / perL, c = i - l * perL;
    const bf16 v = (*flag) ? (bf16)((const float*)src)[i] : ((const bf16*)src)[i];
    dst[l * dstStride + off + c] = v;
  }
}

// ====  weight transpose+normalize: (K x N) -> (N x K) bf16, strided dst  =====
__global__ void wtrans_k(const void* __restrict__ src, bf16* __restrict__ dst,
                         int K, int N, int layer, int dstLS, int dstOff,
                         const int* __restrict__ flag)
{
  __shared__ bf16 t[32][33];
  const size_t sOff = (size_t)(blockIdx.z + layer) * K * N;
  const size_t dOff = (size_t)blockIdx.z * dstLS + dstOff;
  const int n0 = blockIdx.x * 32, k0 = blockIdx.y * 32;
  const int tx = threadIdx.x, ty = threadIdx.y;   // (32,8)
  const int f = *flag;
#pragma unroll
  for (int i = 0; i < 4; i++) {
    const size_t idx = sOff + (size_t)(k0 + ty*4 + i) * N + n0 + tx;
    t[ty*4+i][tx] = f ? (bf16)((const float*)src)[idx] : ((const bf16*)src)[idx];
  }
  __syncthreads();
#pragma unroll
  for (int i = 0; i < 4; i++)
    dst[dOff + (size_t)(n0 + ty*4 + i) * K + k0 + tx] = t[tx][ty*4+i];
}

// =====================  MFMA GEMM, B^T (N x K) input  =====================
// LDS tile layout: 16B slot s of a 64-row block holds
//   (row = s>>2, kgroup = (s&3) ^ ((s>>3)&3))   [XOR swizzle, conflict-free]
// EPI: 2 = fp32 acc+bias+res_bf16 -> Cf
//      3 = bf16 gelu_fast(acc+bias) -> Cb
//      5 = fused QKV routing: nn<768 -> Cb=q (*0.125); <1536 -> Cb2=k;
//          else Cb3 = v^T per-head [((b*NH+h)*DH+d)*SEQ+s]
// XS: 1 = XCD-aware block swizzle (requires gridDim.y % 8 == 0)
template<int BM, int BN, int MT, int NT, int EPI, int XS>
__global__ __launch_bounds__(256)
void gemm_bt(const bf16* __restrict__ A, const bf16* __restrict__ Bt,
             float* __restrict__ Cf, bf16* __restrict__ Cb,
             bf16* __restrict__ Cb2, bf16* __restrict__ Cb3,
             const bf16* __restrict__ bias, const bf16* __restrict__ res,
             int K, int sA, int sB, int sC)
{
  __shared__ __align__(16) bf16 ldsA[BM*32];
  __shared__ __align__(16) bf16 ldsB[BN*32];
  const int tid  = threadIdx.x;
  const int wave = tid >> 6;
  const int lane = tid & 63;
  const int quad = lane >> 4;
  const int l16  = lane & 15;
  const int wm = wave >> 1, wn = wave & 1;   // 2x2 wave grid
  const int swz = (l16 >> 1) & 3;            // read-side XOR swizzle key

  int bx = blockIdx.x, by = blockIdx.y;
  if (XS) {
    if ((gridDim.y & 7) == 0) {
      const int id  = by * gridDim.x + bx;
      const int xcd = id & 7, slot = id >> 3;
      bx = slot % gridDim.x;
      by = (slot / gridDim.x) * 8 + xcd;
    }
  }
  const int m0 = by * BM;
  const int n0 = bx * BN;
  const int srow = tid >> 2;
  const int scol = (((tid & 3) ^ ((tid >> 3) & 3))) * 8;   // swizzled gather

  const bf16* gA = A + (size_t)(m0 + srow) * sA + scol;
  const bf16* gB = Bt + (size_t)(n0 + srow) * sB + scol;
  bf16* lA = &ldsA[(wave * 16) * 32];
  bf16* lB = &ldsB[(wave * 16) * 32];

  f32x4 acc[MT][NT];
  const f32x4 fzero = {0.f, 0.f, 0.f, 0.f};
#pragma unroll
  for (int i = 0; i < MT; i++)
#pragma unroll
    for (int j = 0; j < NT; j++) acc[i][j] = fzero;

  for (int k0 = 0; k0 < K; k0 += 32) {
#pragma unroll
    for (int p = 0; p < BM/64; p++)
      async_copy16(gA + (size_t)p * 64 * sA + k0, lA + p * 64 * 32);
#pragma unroll
    for (int p = 0; p < BN/64; p++)
      async_copy16(gB + (size_t)p * 64 * sB + k0, lB + p * 64 * 32);
    __syncthreads();

    bf16x8 af[MT], bfv[NT];
#pragma unroll
    for (int i = 0; i < MT; i++)
      af[i] = *(const bf16x8*)&ldsA[(wm*(MT*16) + i*16 + l16) * 32 + (quad ^ swz) * 8];
#pragma unroll
    for (int j = 0; j < NT; j++)
      bfv[j] = *(const bf16x8*)&ldsB[(wn*(NT*16) + j*16 + l16) * 32 + (quad ^ swz) * 8];
#pragma unroll
    for (int i = 0; i < MT; i++)
#pragma unroll
      for (int j = 0; j < NT; j++)
        acc[i][j] = __builtin_amdgcn_mfma_f32_16x16x32_bf16(af[i], bfv[j], acc[i][j], 0, 0, 0);
    __syncthreads();
  }

  // epilogue: C/D layout col=lane&15, row=quad*4+reg
#pragma unroll
  for (int i = 0; i < MT; i++) {
    const int mtile = m0 + wm*(MT*16) + i*16 + quad*4;
#pragma unroll
    for (int j = 0; j < NT; j++) {
      const int nn = n0 + wn*(NT*16) + j*16 + l16;
      const float bv = bias ? (float)bias[nn] : 0.f;
      if (EPI == 5) {
        if (nn < HDIM) {
#pragma unroll
          for (int r = 0; r < 4; r++)
            Cb[(size_t)(mtile + r) * HDIM + nn] = (bf16)((acc[i][j][r] + bv) * 0.125f);
        } else if (nn < 2*HDIM) {
#pragma unroll
          for (int r = 0; r < 4; r++)
            Cb2[(size_t)(mtile + r) * HDIM + (nn - HDIM)] = (bf16)(acc[i][j][r] + bv);
        } else {
          const int nn2 = nn - 2*HDIM;
          const int bb = mtile >> 9, s = mtile & 511;
          const int hh = nn2 >> 6, dd = nn2 & 63;
          const size_t base = ((size_t)(bb*NHEAD + hh) * DHEAD + dd) * SEQ + s;
          bf16x4 pk;
#pragma unroll
          for (int r = 0; r < 4; r++) pk[r] = (bf16)(acc[i][j][r] + bv);
          *(bf16x4*)(Cb3 + base) = pk;
        }
      } else {
#pragma unroll
        for (int r = 0; r < 4; r++) {
          const int mm = mtile + r;
          const size_t idx = (size_t)mm * sC + nn;
          const float v = acc[i][j][r];
          if (EPI == 2) Cf[idx] = v + bv + (float)res[idx];
          else if (EPI == 3) Cb[idx] = (bf16)gelu_fast(v + bv);
        }
      }
    }
  }
}

// =====================  fused flash attention  =====================
__global__ __launch_bounds__(256)
void flash_k(const bf16* __restrict__ qb, const bf16* __restrict__ kb,
             const bf16* __restrict__ vt, bf16* __restrict__ ctxb)
{
  __shared__ __align__(16) bf16 Qs[128][72];
  __shared__ __align__(16) bf16 Ks[64][72];
  __shared__ __align__(16) bf16 Vs[64][72];
  __shared__ __align__(16) bf16 Ps[128][72];
  const int tid = threadIdx.x;
  const int wave = tid >> 6, lane = tid & 63;
  const int quad = lane >> 4, l16 = lane & 15;
  const int z = blockIdx.y;
  const int b = z / NHEAD, h = z - b * NHEAD;
  const int qt = blockIdx.x;
  const size_t qRow0 = (size_t)b * SEQ + qt * 128;

#pragma unroll
  for (int r = 0; r < 4; r++) {
    const int idx = tid + r * 256;
    const int row = idx >> 3, c8 = (idx & 7) * 8;
    *(bf16x8*)&Qs[row][c8] =
        *(const bf16x8*)&qb[(qRow0 + row) * HDIM + h * DHEAD + c8];
  }

  f32x4 Oacc[2][4];
  float mrow[2][4], lrow[2][4];
#pragma unroll
  for (int i = 0; i < 2; i++)
#pragma unroll
    for (int n = 0; n < 4; n++) Oacc[i][n] = (f32x4){0.f,0.f,0.f,0.f};
#pragma unroll
  for (int i = 0; i < 2; i++)
#pragma unroll
    for (int r = 0; r < 4; r++) { mrow[i][r] = -3.0e38f; lrow[i][r] = 0.f; }

  for (int j = 0; j < 8; j++) {
    __syncthreads();
#pragma unroll
    for (int r = 0; r < 2; r++) {
      const int idx = tid + r * 256;
      const int row = idx >> 3, c8 = (idx & 7) * 8;
      *(bf16x8*)&Ks[row][c8] =
          *(const bf16x8*)&kb[((size_t)b*SEQ + j*64 + row) * HDIM + h*DHEAD + c8];
      *(bf16x8*)&Vs[row][c8] =
          *(const bf16x8*)&vt[((size_t)z*DHEAD + row) * SEQ + j*64 + c8];
    }
    __syncthreads();

    f32x4 Sacc[2][4];
#pragma unroll
    for (int i = 0; i < 2; i++)
#pragma unroll
      for (int n = 0; n < 4; n++) Sacc[i][n] = (f32x4){0.f,0.f,0.f,0.f};
#pragma unroll
    for (int kk = 0; kk < 2; kk++) {
      bf16x8 af[2], bv[4];
#pragma unroll
      for (int i = 0; i < 2; i++)
        af[i] = *(const bf16x8*)&Qs[wave*32 + i*16 + l16][kk*32 + quad*8];
#pragma unroll
      for (int n = 0; n < 4; n++)
        bv[n] = *(const bf16x8*)&Ks[n*16 + l16][kk*32 + quad*8];
#pragma unroll
      for (int i = 0; i < 2; i++)
#pragma unroll
        for (int n = 0; n < 4; n++)
          Sacc[i][n] = __builtin_amdgcn_mfma_f32_16x16x32_bf16(af[i], bv[n], Sacc[i][n], 0,0,0);
    }

    float alpha[2][4];
#pragma unroll
    for (int i = 0; i < 2; i++)
#pragma unroll
      for (int r = 0; r < 4; r++) {
        float mx = Sacc[i][0][r];
#pragma unroll
        for (int n = 1; n < 4; n++) mx = fmaxf(mx, Sacc[i][n][r]);
#pragma unroll
        for (int o = 8; o; o >>= 1) mx = fmaxf(mx, __shfl_xor(mx, o));
        const float mn = fmaxf(mrow[i][r], mx);
        const float a = __expf(mrow[i][r] - mn);
        float rs = 0.f;
#pragma unroll
        for (int n = 0; n < 4; n++) {
          const float p = __expf(Sacc[i][n][r] - mn);
          Sacc[i][n][r] = p; rs += p;
        }
#pragma unroll
        for (int o = 8; o; o >>= 1) rs += __shfl_xor(rs, o);
        lrow[i][r] = lrow[i][r] * a + rs;
        mrow[i][r] = mn;
        alpha[i][r] = a;
      }

#pragma unroll
    for (int i = 0; i < 2; i++)
#pragma unroll
      for (int n = 0; n < 4; n++)
#pragma unroll
        for (int r = 0; r < 4; r++)
          Ps[wave*32 + i*16 + quad*4 + r][n*16 + l16] = (bf16)Sacc[i][n][r];
    __syncthreads();

#pragma unroll
    for (int i = 0; i < 2; i++)
#pragma unroll
      for (int n = 0; n < 4; n++)
#pragma unroll
        for (int r = 0; r < 4; r++) Oacc[i][n][r] *= alpha[i][r];
#pragma unroll
    for (int kk = 0; kk < 2; kk++) {
      bf16x8 af[2], bv[4];
#pragma unroll
      for (int i = 0; i < 2; i++)
        af[i] = *(const bf16x8*)&Ps[wave*32 + i*16 + l16][kk*32 + quad*8];
#pragma unroll
      for (int n = 0; n < 4; n++)
        bv[n] = *(const bf16x8*)&Vs[n*16 + l16][kk*32 + quad*8];
#pragma unroll
      for (int i = 0; i < 2; i++)
#pragma unroll
        for (int n = 0; n < 4; n++)
          Oacc[i][n] = __builtin_amdgcn_mfma_f32_16x16x32_bf16(af[i], bv[n], Oacc[i][n], 0,0,0);
    }
  }

#pragma unroll
  for (int i = 0; i < 2; i++)
#pragma unroll
    for (int r = 0; r < 4; r++) {
      const float inv = 1.f / lrow[i][r];
      const size_t tok = qRow0 + wave*32 + i*16 + quad*4 + r;
#pragma unroll
      for (int n = 0; n < 4; n++)
        ctxb[tok * HDIM + h*DHEAD + n*16 + l16] = (bf16)(Oacc[i][n][r] * inv);
    }
}

// ========  LayerNorm over H=768, fp32 in, bf16 out (+ optional d_out)  ========
__global__ void layernorm_k(const float* __restrict__ x, const bf16* __restrict__ g,
                            const bf16* __restrict__ b, bf16* __restrict__ yb,
                            void* __restrict__ dout, int last, const int* __restrict__ flag)
{
  __shared__ float sred[4];
  const int row = blockIdx.x;
  const int tid = threadIdx.x;
  const float* xr = x + (size_t)row * HDIM;
  const float v0 = xr[tid], v1 = xr[tid+256], v2 = xr[tid+512];
  float s = v0 + v1 + v2;
#pragma unroll
  for (int o = 32; o; o >>= 1) s += __shfl_xor(s, o);
  if ((tid & 63) == 0) sred[tid >> 6] = s;
  __syncthreads();
  const float mean = (sred[0]+sred[1]+sred[2]+sred[3]) * (1.f/768.f);
  __syncthreads();
  const float d0 = v0-mean, d1 = v1-mean, d2 = v2-mean;
  float vs = d0*d0 + d1*d1 + d2*d2;
#pragma unroll
  for (int o = 32; o; o >>= 1) vs += __shfl_xor(vs, o);
  if ((tid & 63) == 0) sred[tid >> 6] = vs;
  __syncthreads();
  const float var = (sred[0]+sred[1]+sred[2]+sred[3]) * (1.f/768.f);
  const float rs  = rsqrtf(var + 1e-12f);
  const float y0 = d0*rs*(float)g[tid]     + (float)b[tid];
  const float y1 = d1*rs*(float)g[tid+256] + (float)b[tid+256];
  const float y2 = d2*rs*(float)g[tid+512] + (float)b[tid+512];
  bf16* ybr = yb + (size_t)row * HDIM;
  ybr[tid]     = (bf16)y0;
  ybr[tid+256] = (bf16)y1;
  ybr[tid+512] = (bf16)y2;
  if (last) {
    if (*flag) {
      float* o = (float*)dout + (size_t)row * HDIM;
      o[tid] = y0; o[tid+256] = y1; o[tid+512] = y2;
    } else {
      bf16* o = (bf16*)dout + (size_t)row * HDIM;
      o[tid] = (bf16)y0; o[tid+256] = (bf16)y1; o[tid+512] = (bf16)y2;
    }
  }
}

// ============================================================================
extern "C" void kernel_launch(void* const* d_in, const int* in_sizes, int n_in,
                              void* d_out, int out_size, void* d_ws, size_t ws_size,
                              hipStream_t stream)
{
  (void)in_sizes; (void)n_in; (void)out_size;

  char* ws = (char*)d_ws;
  size_t off = 0;
  auto carve = [&](size_t bytes) -> char* {
    char* p = ws + off; off += (bytes + 255) & ~(size_t)255; return p;
  };
  int*   flag = (int*)carve(256);
  bf16*  hcur = (bf16*)carve((size_t)MTOK*HDIM*2);
  bf16*  qb   = (bf16*)carve((size_t)MTOK*HDIM*2);
  bf16*  kb   = (bf16*)carve((size_t)MTOK*HDIM*2);
  bf16*  vt   = (bf16*)carve((size_t)MTOK*HDIM*2);
  bf16*  ctxb = (bf16*)carve((size_t)MTOK*HDIM*2);
  float* x1   = (float*)carve((size_t)MTOK*HDIM*4);
  bf16*  aob  = kb;   // kb dead once flash attention of the layer is complete

  bf16* nbqkv = (bf16*)carve((size_t)LNUM*NQKV*2);
  bf16* nbo   = (bf16*)carve((size_t)LNUM*HDIM*2);
  bf16* ng1   = (bf16*)carve((size_t)LNUM*HDIM*2);
  bf16* nb1   = (bf16*)carve((size_t)LNUM*HDIM*2);
  bf16* nbi   = (bf16*)carve((size_t)LNUM*IDIM*2);
  bf16* nbo2  = (bf16*)carve((size_t)LNUM*HDIM*2);
  bf16* ng2   = (bf16*)carve((size_t)LNUM*HDIM*2);
  bf16* nb2   = (bf16*)carve((size_t)LNUM*HDIM*2);

  const size_t wAllBytes = (size_t)LNUM*(NQKV*HDIM + HDIM*HDIM + 2*HDIM*IDIM)*2; // ~84.9MB
  const bool preAll = ws_size >= off + wAllBytes + (size_t)256*IDIM*2 + (1u<<20);
  bf16 *wqkvt=0, *wot=0, *wit=0, *wo2t=0, *bufA=0, *bufB=0;
  if (preAll) {
    wqkvt = (bf16*)carve((size_t)LNUM*NQKV*HDIM*2);
    wot   = (bf16*)carve((size_t)LNUM*HDIM*HDIM*2);
    wit   = (bf16*)carve((size_t)LNUM*HDIM*IDIM*2);
    wo2t  = (bf16*)carve((size_t)LNUM*HDIM*IDIM*2);
  } else {
    bufA = (bf16*)carve((size_t)HDIM*IDIM*2);
    bufB = (bf16*)carve((size_t)HDIM*IDIM*2);
  }

  const size_t unionAvail = (ws_size > off) ? (ws_size - off) : 0;
  int RM = 256;
  { const int rms[6] = {8192,4096,2048,1024,512,256};
    for (int i = 0; i < 6; i++)
      if ((size_t)rms[i]*IDIM*2 <= unionAvail) { RM = rms[i]; break; } }
  bf16* interb = (bf16*)(ws + off);

  // ---------------- normalize inputs ----------------------------------------
  detect_k<<<1, 256, 0, stream>>>((const unsigned short*)d_in[1], flag);
  cvt1d_k<<<(MTOK*HDIM+255)/256, 256, 0, stream>>>(d_in[0], hcur, MTOK*HDIM, flag);
  cvt_slice_k<<<(LNUM*HDIM+255)/256, 256, 0, stream>>>(d_in[2], nbqkv, HDIM, 0,      NQKV, LNUM*HDIM, flag);
  cvt_slice_k<<<(LNUM*HDIM+255)/256, 256, 0, stream>>>(d_in[4], nbqkv, HDIM, HDIM,   NQKV, LNUM*HDIM, flag);
  cvt_slice_k<<<(LNUM*HDIM+255)/256, 256, 0, stream>>>(d_in[6], nbqkv, HDIM, 2*HDIM, NQKV, LNUM*HDIM, flag);
  cvt1d_k<<<(LNUM*HDIM+255)/256, 256, 0, stream>>>(d_in[8],  nbo,  LNUM*HDIM, flag);
  cvt1d_k<<<(LNUM*HDIM+255)/256, 256, 0, stream>>>(d_in[9],  ng1,  LNUM*HDIM, flag);
  cvt1d_k<<<(LNUM*HDIM+255)/256, 256, 0, stream>>>(d_in[10], nb1,  LNUM*HDIM, flag);
  cvt1d_k<<<(LNUM*IDIM+255)/256, 256, 0, stream>>>(d_in[12], nbi,  LNUM*IDIM, flag);
  cvt1d_k<<<(LNUM*HDIM+255)/256, 256, 0, stream>>>(d_in[14], nbo2, LNUM*HDIM, flag);
  cvt1d_k<<<(LNUM*HDIM+255)/256, 256, 0, stream>>>(d_in[15], ng2,  LNUM*HDIM, flag);
  cvt1d_k<<<(LNUM*HDIM+255)/256, 256, 0, stream>>>(d_in[16], nb2,  LNUM*HDIM, flag);

  const dim3 tb(32, 8);
  if (preAll) {
    wtrans_k<<<dim3(HDIM/32, HDIM/32, LNUM), tb, 0, stream>>>(d_in[1], wqkvt, HDIM, HDIM, 0, NQKV*HDIM, 0,           flag);
    wtrans_k<<<dim3(HDIM/32, HDIM/32, LNUM), tb, 0, stream>>>(d_in[3], wqkvt, HDIM, HDIM, 0, NQKV*HDIM, HDIM*HDIM,   flag);
    wtrans_k<<<dim3(HDIM/32, HDIM/32, LNUM), tb, 0, stream>>>(d_in[5], wqkvt, HDIM, HDIM, 0, NQKV*HDIM, 2*HDIM*HDIM, flag);
    wtrans_k<<<dim3(HDIM/32, HDIM/32, LNUM), tb, 0, stream>>>(d_in[7], wot,  HDIM, HDIM, 0, HDIM*HDIM, 0, flag);
    wtrans_k<<<dim3(IDIM/32, HDIM/32, LNUM), tb, 0, stream>>>(d_in[11], wit,  HDIM, IDIM, 0, HDIM*IDIM, 0, flag);
    wtrans_k<<<dim3(HDIM/32, IDIM/32, LNUM), tb, 0, stream>>>(d_in[13], wo2t, IDIM, HDIM, 0, HDIM*IDIM, 0, flag);
  }

  for (int l = 0; l < LNUM; l++) {
    const bf16* hin = hcur;

    // ---- fused QKV ----
    const bf16* WqkvT;
    if (preAll) WqkvT = wqkvt + (size_t)l * NQKV * HDIM;
    else {
      wtrans_k<<<dim3(HDIM/32, HDIM/32, 1), tb, 0, stream>>>(d_in[1], bufA, HDIM, HDIM, l, 0, 0,           flag);
      wtrans_k<<<dim3(HDIM/32, HDIM/32, 1), tb, 0, stream>>>(d_in[3], bufA, HDIM, HDIM, l, 0, HDIM*HDIM,   flag);
      wtrans_k<<<dim3(HDIM/32, HDIM/32, 1), tb, 0, stream>>>(d_in[5], bufA, HDIM, HDIM, l, 0, 2*HDIM*HDIM, flag);
      WqkvT = bufA;
    }
    gemm_bt<128,128,4,4,5,1><<<dim3(NQKV/128, MTOK/128), 256, 0, stream>>>(
        hin, WqkvT, nullptr, qb, kb, vt, nbqkv + (size_t)l*NQKV, nullptr,
        HDIM, HDIM, HDIM, HDIM);

    // ---- fused flash attention ----
    flash_k<<<dim3(SEQ/128, NB*NHEAD), 256, 0, stream>>>(qb, kb, vt, ctxb);

    // ---- x1 = ctx@Wo + bo + h ; attn_out = LN(x1) -> aob ----
    const bf16* WoT;
    if (preAll) WoT = wot + (size_t)l * HDIM * HDIM;
    else {
      wtrans_k<<<dim3(HDIM/32, HDIM/32, 1), tb, 0, stream>>>(d_in[7], bufA, HDIM, HDIM, l, 0, 0, flag);
      WoT = bufA;
    }
    gemm_bt<128,128,4,4,2,1><<<dim3(HDIM/128, MTOK/128), 256, 0, stream>>>(
        ctxb, WoT, x1, nullptr, nullptr, nullptr, nbo + l*HDIM, hin,
        HDIM, HDIM, HDIM, HDIM);
    layernorm_k<<<MTOK, 256, 0, stream>>>(x1, ng1 + l*HDIM, nb1 + l*HDIM, aob,
                                          d_out, 0, flag);

    // ---- FFN ----
    const bf16 *WiT, *Wo2T;
    if (preAll) { WiT = wit + (size_t)l*HDIM*IDIM; Wo2T = wo2t + (size_t)l*HDIM*IDIM; }
    else {
      wtrans_k<<<dim3(IDIM/32, HDIM/32, 1), tb, 0, stream>>>(d_in[11], bufA, HDIM, IDIM, l, 0, 0, flag);
      wtrans_k<<<dim3(HDIM/32, IDIM/32, 1), tb, 0, stream>>>(d_in[13], bufB, IDIM, HDIM, l, 0, 0, flag);
      WiT = bufA; Wo2T = bufB;
    }
    for (int r0 = 0; r0 < MTOK; r0 += RM) {
      gemm_bt<128,128,4,4,3,1><<<dim3(IDIM/128, RM/128), 256, 0, stream>>>(
          aob + (size_t)r0*HDIM, WiT, nullptr, interb, nullptr, nullptr,
          nbi + (size_t)l*IDIM, nullptr, HDIM, HDIM, HDIM, IDIM);
      gemm_bt<128,128,4,4,2,1><<<dim3(HDIM/128, RM/128), 256, 0, stream>>>(
          interb, Wo2T, x1 + (size_t)r0*HDIM, nullptr, nullptr, nullptr,
          nbo2 + l*HDIM, aob + (size_t)r0*HDIM, IDIM, IDIM, IDIM, HDIM);
    }
    layernorm_k<<<MTOK, 256, 0, stream>>>(x1, ng2 + l*HDIM, nb2 + l*HDIM, hcur,
                                          d_out, (l == LNUM-1) ? 1 : 0, flag);
  }
}